// Round 12
// baseline (101.194 us; speedup 1.0000x reference)
//
#include <hip/hip_runtime.h>
#include <math.h>

#define DPI 3.14159265358979323846

__device__ __forceinline__ float2 cmul(float2 a, float2 b) {
    return make_float2(a.x*b.x - a.y*b.y, a.x*b.y + a.y*b.x);
}
__device__ __forceinline__ float2 cadd(float2 a, float2 b){ return make_float2(a.x+b.x, a.y+b.y); }
__device__ __forceinline__ float2 csub(float2 a, float2 b){ return make_float2(a.x-b.x, a.y-b.y); }

// W_32^m = (cos, -sin)(2*pi*m/32), m = 0..15
__device__ const float TW32R[16] = {
    1.0f, 0.98078528040323045f, 0.92387953251128676f, 0.83146961230254524f,
    0.70710678118654752f, 0.55557023301960222f, 0.38268343236508977f, 0.19509032201612827f,
    0.0f, -0.19509032201612827f, -0.38268343236508977f, -0.55557023301960222f,
    -0.70710678118654752f, -0.83146961230254524f, -0.92387953251128676f, -0.98078528040323045f };
__device__ const float TW32I[16] = {
    0.0f, -0.19509032201612827f, -0.38268343236508977f, -0.55557023301960222f,
    -0.70710678118654752f, -0.83146961230254524f, -0.92387953251128676f, -0.98078528040323045f,
    -1.0f, -0.98078528040323045f, -0.92387953251128676f, -0.83146961230254524f,
    -0.70710678118654752f, -0.55557023301960222f, -0.38268343236508977f, -0.19509032201612827f };

__device__ const int BR4[16] = {0,8,4,12,2,10,6,14,1,9,5,13,3,11,7,15};

// DIF stage for register FFT of size 16, butterfly half-span H.
template<int H>
__device__ __forceinline__ void stage16(float2* y) {
    #pragma unroll
    for (int g = 0; g < 16; g += 2*H) {
        #pragma unroll
        for (int j = 0; j < H; j++) {
            float2 u = y[g+j], v = y[g+j+H];
            y[g+j] = cadd(u, v);
            float2 d = csub(u, v);
            const int m = j * (16 / H);
            y[g+j+H] = (j == 0) ? d : cmul(d, make_float2(TW32R[m], TW32I[m]));
        }
    }
}
__device__ __forceinline__ void fft16(float2* y) {
    stage16<8>(y); stage16<4>(y); stage16<2>(y); stage16<1>(y);
}   // y[p] = OUT[BR4[p]]

// wp[m] = w^m, m=0..8 only (18 VGPRs instead of 32); m>8 composed at use site.
__device__ __forceinline__ void pow9(float2 w, float2* wp) {
    wp[0] = make_float2(1.f, 0.f);
    wp[1] = w;
    wp[2] = cmul(w, w);
    wp[3] = cmul(wp[2], w);
    wp[4] = cmul(wp[2], wp[2]);
    wp[5] = cmul(wp[4], wp[1]);
    wp[6] = cmul(wp[4], wp[2]);
    wp[7] = cmul(wp[4], wp[3]);
    wp[8] = cmul(wp[4], wp[4]);
}

// ws layout (float2):
// [0,512)      W_8192^u   (stage-1 pow9 base)
// [512,544)    W_512^j    (stage-2 pow9 base)
// [544,1056)   W_1024^t   (unpack base, k=16t+i)
// [1056,1072)  W_16384^i  (i<16)
static __global__ void init_tw(float2* __restrict__ ws) {
    int g = blockIdx.x * 1024 + threadIdx.x;
    if (g < 512) {
        ws[g] = make_float2((float)cos(DPI*g/4096.0), (float)(-sin(DPI*g/4096.0)));
    } else if (g < 544) {
        int j = g - 512;
        ws[g] = make_float2((float)cos(DPI*j/256.0), (float)(-sin(DPI*j/256.0)));
    } else if (g < 1056) {
        int q = g - 544;
        ws[g] = make_float2((float)cos(DPI*q/512.0), (float)(-sin(DPI*q/512.0)));
    } else if (g < 1072) {
        int i = g - 1056;
        ws[g] = make_float2((float)cos(DPI*i/8192.0), (float)(-sin(DPI*i/8192.0)));
    }
}

__launch_bounds__(512, 2)   // 512-thread blocks compile at 128 VGPRs (r3/r11-verified)
static __global__ void chisq_kernel(const float* __restrict__ tmpl,
                                    const float* __restrict__ strn,
                                    const float2* __restrict__ ws,
                                    float* __restrict__ out)
{
    __shared__ float2 Z[8192];                  // 64 KiB, one spectrum at a time
    float* F = reinterpret_cast<float*>(Z);
    int*   I = reinterpret_cast<int*>(Z);

    const int t   = threadIdx.x;                // 0..511
    const int row = blockIdx.x;
    const float ALPHA = 1.1920928955078125e-7f; // 4*DF/fs^2 = 2^-23

    const float2* tw8192 = ws;                  // W_8192^u
    const float2* tw512  = ws + 512;            // W_512^j
    const float2* twB    = ws + 544;            // W_1024^t
    const float2* twI    = ws + 1056;           // W_16384^i, i<16

    const int k1s = t >> 5, js = t & 31;        // stage-2 coords
    const int f = t >> 8, k1t = (t >> 4) & 15, k2t = t & 15;   // stage-3 coords

    // -------- issue BOTH rows' loads up front: strain first, template second --------
    float2 y[16], hY[16];
    {
        const float2* xs = reinterpret_cast<const float2*>(strn + (size_t)row * 16384);
        #pragma unroll
        for (int n1 = 0; n1 < 16; n1++) y[n1] = xs[n1*512 + t];
        __builtin_amdgcn_sched_barrier(0);      // pin: strain loads issued first
        const float2* xh = reinterpret_cast<const float2*>(tmpl + (size_t)row * 16384);
        #pragma unroll
        for (int n1 = 0; n1 < 16; n1++) hY[n1] = xh[n1*512 + t];
        __builtin_amdgcn_sched_barrier(0);      // pin: template loads in flight behind them
    }

    // -------- 8192-point FFT pipeline, data already in yy[16] --------
    // Caller guarantees Z consumers are done before first store. 5 internal barriers.
    auto do_fft = [&](float2* yy) {
        fft16(yy);
        {
            float2 wp[9]; pow9(tw8192[t], wp);
            #pragma unroll
            for (int p = 0; p < 16; p++) {
                int k1 = BR4[p];
                float2 val = yy[p];
                if (k1 > 0) {
                    float2 tw = (k1 <= 8) ? wp[k1] : cmul(wp[k1-8], wp[8]);
                    val = cmul(val, tw);
                }
                Z[(t << 4) | (k1 ^ (t & 15))] = val;   // L1[u][k1], swizzled
            }
        }
        __syncthreads();
        #pragma unroll
        for (int n2 = 0; n2 < 16; n2++)
            yy[n2] = Z[((n2*32 + js) << 4) | (k1s ^ (js & 15))];
        __syncthreads();                         // all L1 reads done before L2 writes
        fft16(yy);
        {
            float2 wq[9]; pow9(tw512[js], wq);
            #pragma unroll
            for (int p = 0; p < 16; p++) {
                int k2 = BR4[p];
                float2 val = yy[p];
                if (k2 > 0) {
                    float2 tw = (k2 <= 8) ? wq[k2] : cmul(wq[k2-8], wq[8]);
                    val = cmul(val, tw);
                }
                Z[(k1s << 9) + (k2 << 5) + (js ^ k2)] = val;  // L2[k1][k2][j], swizzled
            }
        }
        __syncthreads();
        const int base = (k1t << 9) + (k2t << 5);
        if (f == 0) {
            #pragma unroll
            for (int j2 = 0; j2 < 16; j2++) {
                float2 a = Z[base + (j2 ^ k2t)];
                float2 b = Z[base + (j2 ^ k2t) + 16];
                yy[j2] = cadd(a, b);
            }
        } else {
            #pragma unroll
            for (int j2 = 0; j2 < 16; j2++) {
                float2 a = Z[base + (j2 ^ k2t)];
                float2 b = Z[base + (j2 ^ k2t) + 16];
                yy[j2] = cmul(csub(a, b), make_float2(TW32R[j2], TW32I[j2]));
            }
        }
        __syncthreads();                         // all L2 reads done before spectrum store
        fft16(yy);
        #pragma unroll
        for (int p = 0; p < 16; p++) {
            int s2 = BR4[p];
            int k = k1t + (k2t << 4) + (f << 8) + (s2 << 9);
            Z[(k & ~31) | ((k & 31) ^ ((k >> 5) & 31))] = yy[p];  // natural k, swizzled low5
        }
        __syncthreads();                         // spectrum ready
    };

    // -------- phase A: strain FFT + unpack S spectrum (16 bins/thread) --------
    float sre[16], sim[16];                      // S spectrum; later |H|^2 / Re(conj H * S)
    float s_nyq;
    do_fft(y);
    {
        const float2 cv = twB[t];
        #pragma unroll
        for (int i = 0; i < 16; i++) {
            int k = (t << 4) + i;
            int m = (8192 - k) & 8191;
            int ak = (k & ~31) | ((k & 31) ^ ((k >> 5) & 31));
            int am = (m & ~31) | ((m & 31) ^ ((m >> 5) & 31));
            float2 A = Z[ak], B = Z[am];
            float2 w = cmul(cv, twI[i]);         // W_16384^k
            float Er = 0.5f*(A.x + B.x), Ei = 0.5f*(A.y - B.y);
            float Dr = 0.5f*(A.x - B.x), Di = 0.5f*(A.y + B.y);
            sre[i] = Er + w.x*Di + w.y*Dr;
            sim[i] = Ei + w.y*Di - w.x*Dr;
        }
        float2 z0 = Z[0];
        s_nyq = z0.x - z0.y;
    }
    __syncthreads();                             // unpack reads done; Z free

    // -------- phase B: template FFT (data already in hY) + unpack + in-place combine --------
    float h_nyq;
    do_fft(hY);
    {
        const float2 cv = twB[t];
        #pragma unroll
        for (int i = 0; i < 16; i++) {
            int k = (t << 4) + i;
            int m = (8192 - k) & 8191;
            int ak = (k & ~31) | ((k & 31) ^ ((k >> 5) & 31));
            int am = (m & ~31) | ((m & 31) ^ ((m >> 5) & 31));
            float2 A = Z[ak], B = Z[am];
            float2 w = cmul(cv, twI[i]);
            float Er = 0.5f*(A.x + B.x), Ei = 0.5f*(A.y - B.y);
            float Dr = 0.5f*(A.x - B.x), Di = 0.5f*(A.y + B.y);
            float hr = Er + w.x*Di + w.y*Dr;
            float hi = Ei + w.y*Di - w.x*Dr;
            float pr = hr*sre[i] + hi*sim[i];    // Re(conj(H)*S)
            sre[i] = hr*hr + hi*hi;              // |H|^2   (in place: never 64 live floats)
            sim[i] = pr;
        }
        float2 z0 = Z[0];
        h_nyq = z0.x - z0.y;
    }
    __syncthreads();                             // unpack reads done; Z free for cum

    // -------- cum_h: wave shuffle scan over 8 waves --------
    const int SCANW = 8456;                      // beyond cum (<= F[8448])
    const int EDG   = 8466;                      // 17 ints
    const int BINS  = 8484;                      // 16 floats
    const int TOT   = 8501;

    float run = 0.f;
    #pragma unroll
    for (int i = 0; i < 16; i++) run += ALPHA * sre[i];

    const int lane = t & 63, wid = t >> 6;
    float v = run;
    #pragma unroll
    for (int off = 1; off < 64; off <<= 1) {
        float o = __shfl_up(v, off, 64);
        if (lane >= off) v += o;
    }
    if (lane == 63) F[SCANW + wid] = v;
    __syncthreads();
    float wbase = 0.f;
    #pragma unroll
    for (int w2 = 0; w2 < 7; w2++) if (w2 < wid) wbase += F[SCANW + w2];
    float base2 = wbase + v - run;               // exclusive prefix

    float cum = base2;
    #pragma unroll
    for (int i = 0; i < 16; i++) {               // cum at phys(k)=k+(k>>5)
        cum += ALPHA * sre[i];
        int k = (t << 4) + i;
        F[k + (k >> 5)] = cum;
    }
    if (t == 511) F[8448] = cum + ALPHA * h_nyq * h_nyq;   // cum_h[8192]
    __syncthreads();

    // -------- edges (searchsorted right) + bin init --------
    float total_h = F[8448];
    if (t < 17) {
        float target = (float)t * 0.0625f * total_h;
        int lo = 0, hi = 8193;
        while (lo < hi) {
            int mid = (lo + hi) >> 1;
            float vv = F[mid + (mid >> 5)];
            if (vv <= target) lo = mid + 1; else hi = mid;
        }
        I[EDG + t] = lo < 8192 ? lo : 8192;
    }
    if (t >= 64 && t < 80) F[BINS + (t - 64)] = 0.f;
    if (t == 80) F[TOT] = 0.f;
    __syncthreads();

    int e[17];
    #pragma unroll
    for (int i = 0; i < 17; i++) e[i] = I[EDG + i];

    float invs = 1.0f / sqrtf(total_h);
    float qs   = ALPHA * invs;

    // -------- segmented bin sums + total --------
    float tot = 0.f, acc = 0.f;
    int   cur = -1;
    #pragma unroll
    for (int i = 0; i < 16; i++) {
        int   k = (t << 4) + i;
        float r = qs * sim[i];
        tot += r;
        int bn = -1;                             // k in bin bn iff e[bn] < k <= e[bn+1]
        #pragma unroll
        for (int j = 0; j < 17; j++) bn += (e[j] < k) ? 1 : 0;
        if (bn != cur) {
            if (cur >= 0) atomicAdd(&F[BINS + cur], acc);
            acc = 0.f;
            cur = bn;
        }
        acc += r;
    }
    if (cur >= 0) atomicAdd(&F[BINS + cur], acc);

    #pragma unroll
    for (int off = 32; off > 0; off >>= 1) tot += __shfl_down(tot, off);
    if ((t & 63) == 0) atomicAdd(&F[TOT], tot);

    if (t == 0) {                                // Nyquist term (k = 8192)
        float rn = qs * (h_nyq * s_nyq);
        atomicAdd(&F[TOT], rn);
        int bn = -1;
        #pragma unroll
        for (int j = 0; j < 17; j++) bn += (e[j] < 8192) ? 1 : 0;
        if (bn >= 0) atomicAdd(&F[BINS + bn], rn);
    }
    __syncthreads();

    if (t == 0) {
        float total = F[TOT];
        float mean  = total * 0.0625f;
        float chisq = 0.f;
        #pragma unroll
        for (int j = 0; j < 16; j++) {
            float d = F[BINS + j] - mean;
            chisq += d * d;
        }
        out[row] = chisq * (16.0f / 15.0f);
    }
}

extern "C" void kernel_launch(void* const* d_in, const int* in_sizes, int n_in,
                              void* d_out, int out_size, void* d_ws, size_t ws_size,
                              hipStream_t stream) {
    const float* tmpl = (const float*)d_in[0];
    const float* strn = (const float*)d_in[1];
    float* outp = (float*)d_out;
    float2* ws  = (float2*)d_ws;                 // ~8.4 KiB twiddle tables

    int rows = in_sizes[0] / 16384;              // 1024

    hipLaunchKernelGGL(init_tw, dim3(2), dim3(1024), 0, stream, ws);
    hipLaunchKernelGGL(chisq_kernel, dim3(rows), dim3(512), 0, stream,
                       tmpl, strn, ws, outp);
}

// Round 13
// 93.079 us; speedup vs baseline: 1.0872x; 1.0872x over previous
//
#include <hip/hip_runtime.h>
#include <math.h>

#define DPI 3.14159265358979323846

__device__ __forceinline__ float2 cmul(float2 a, float2 b) {
    return make_float2(a.x*b.x - a.y*b.y, a.x*b.y + a.y*b.x);
}
__device__ __forceinline__ float2 cadd(float2 a, float2 b){ return make_float2(a.x+b.x, a.y+b.y); }
__device__ __forceinline__ float2 csub(float2 a, float2 b){ return make_float2(a.x-b.x, a.y-b.y); }

// W_32^m = (cos, -sin)(2*pi*m/32), m = 0..15
__device__ const float TW32R[16] = {
    1.0f, 0.98078528040323045f, 0.92387953251128676f, 0.83146961230254524f,
    0.70710678118654752f, 0.55557023301960222f, 0.38268343236508977f, 0.19509032201612827f,
    0.0f, -0.19509032201612827f, -0.38268343236508977f, -0.55557023301960222f,
    -0.70710678118654752f, -0.83146961230254524f, -0.92387953251128676f, -0.98078528040323045f };
__device__ const float TW32I[16] = {
    0.0f, -0.19509032201612827f, -0.38268343236508977f, -0.55557023301960222f,
    -0.70710678118654752f, -0.83146961230254524f, -0.92387953251128676f, -0.98078528040323045f,
    -1.0f, -0.98078528040323045f, -0.92387953251128676f, -0.83146961230254524f,
    -0.70710678118654752f, -0.55557023301960222f, -0.38268343236508977f, -0.19509032201612827f };

__device__ const int BR4[16] = {0,8,4,12,2,10,6,14,1,9,5,13,3,11,7,15};

// DIF stage for register FFT of size 16, butterfly half-span H.
template<int H>
__device__ __forceinline__ void stage16(float2* y) {
    #pragma unroll
    for (int g = 0; g < 16; g += 2*H) {
        #pragma unroll
        for (int j = 0; j < H; j++) {
            float2 u = y[g+j], v = y[g+j+H];
            y[g+j] = cadd(u, v);
            float2 d = csub(u, v);
            const int m = j * (16 / H);
            y[g+j+H] = (j == 0) ? d : cmul(d, make_float2(TW32R[m], TW32I[m]));
        }
    }
}
__device__ __forceinline__ void fft16(float2* y) {
    stage16<8>(y); stage16<4>(y); stage16<2>(y); stage16<1>(y);
}   // y[p] = OUT[BR4[p]]

// wp[m] = w^m, m=0..8 only (18 VGPRs); m>8 composed at use site.
__device__ __forceinline__ void pow9(float2 w, float2* wp) {
    wp[0] = make_float2(1.f, 0.f);
    wp[1] = w;
    wp[2] = cmul(w, w);
    wp[3] = cmul(wp[2], w);
    wp[4] = cmul(wp[2], wp[2]);
    wp[5] = cmul(wp[4], wp[1]);
    wp[6] = cmul(wp[4], wp[2]);
    wp[7] = cmul(wp[4], wp[3]);
    wp[8] = cmul(wp[4], wp[4]);
}

// ws layout (float2):
// [0,512)      W_8192^u   (stage-1 pow9 base)
// [512,544)    W_512^j    (stage-2 pow9 base)
// [544,1056)   W_1024^t   (unpack base, k=16t+i)
// [1056,1072)  W_16384^i  (i<16)
static __global__ void init_tw(float2* __restrict__ ws) {
    int g = blockIdx.x * 1024 + threadIdx.x;
    if (g < 512) {
        ws[g] = make_float2((float)cos(DPI*g/4096.0), (float)(-sin(DPI*g/4096.0)));
    } else if (g < 544) {
        int j = g - 512;
        ws[g] = make_float2((float)cos(DPI*j/256.0), (float)(-sin(DPI*j/256.0)));
    } else if (g < 1056) {
        int q = g - 544;
        ws[g] = make_float2((float)cos(DPI*q/512.0), (float)(-sin(DPI*q/512.0)));
    } else if (g < 1072) {
        int i = g - 1056;
        ws[g] = make_float2((float)cos(DPI*i/8192.0), (float)(-sin(DPI*i/8192.0)));
    }
}

__launch_bounds__(512, 2)   // 512 threads -> 128 VGPRs; 64 KiB LDS -> 2 blocks/CU co-resident
static __global__ void chisq_kernel(const float* __restrict__ tmpl,
                                    const float* __restrict__ strn,
                                    const float2* __restrict__ ws,
                                    float* __restrict__ out)
{
    __shared__ float2 Z[8192];                  // 64 KiB, one spectrum at a time
    float* F = reinterpret_cast<float*>(Z);
    int*   I = reinterpret_cast<int*>(Z);

    const int t   = threadIdx.x;                // 0..511
    const int row = blockIdx.x;
    const float ALPHA = 1.1920928955078125e-7f; // 4*DF/fs^2 = 2^-23

    const float2* tw8192 = ws;                  // W_8192^u
    const float2* tw512  = ws + 512;            // W_512^j
    const float2* twB    = ws + 544;            // W_1024^t
    const float2* twI    = ws + 1056;           // W_16384^i, i<16

    const int k1s = t >> 5, js = t & 31;        // stage-2 coords
    const int f = t >> 8, k1t = (t >> 4) & 15, k2t = t & 15;   // stage-3 coords

    // -------- 8192-point FFT: load row into regs, 3 reg-FFT stages, 2 LDS transposes --------
    // Caller guarantees Z consumers are done before first store. 5 internal barriers.
    auto do_fft = [&](const float* srcrow, float2* yy) {
        const float2* x = reinterpret_cast<const float2*>(srcrow);
        #pragma unroll
        for (int n1 = 0; n1 < 16; n1++) yy[n1] = x[n1*512 + t];
        fft16(yy);
        {
            float2 wp[9]; pow9(tw8192[t], wp);
            #pragma unroll
            for (int p = 0; p < 16; p++) {
                int k1 = BR4[p];
                float2 val = yy[p];
                if (k1 > 0) {
                    float2 tw = (k1 <= 8) ? wp[k1] : cmul(wp[k1-8], wp[8]);
                    val = cmul(val, tw);
                }
                Z[(t << 4) | (k1 ^ (t & 15))] = val;   // L1[u][k1], swizzled
            }
        }
        __syncthreads();
        #pragma unroll
        for (int n2 = 0; n2 < 16; n2++)
            yy[n2] = Z[((n2*32 + js) << 4) | (k1s ^ (js & 15))];
        __syncthreads();                         // all L1 reads done before L2 writes
        fft16(yy);
        {
            float2 wq[9]; pow9(tw512[js], wq);
            #pragma unroll
            for (int p = 0; p < 16; p++) {
                int k2 = BR4[p];
                float2 val = yy[p];
                if (k2 > 0) {
                    float2 tw = (k2 <= 8) ? wq[k2] : cmul(wq[k2-8], wq[8]);
                    val = cmul(val, tw);
                }
                Z[(k1s << 9) + (k2 << 5) + (js ^ k2)] = val;  // L2[k1][k2][j], swizzled
            }
        }
        __syncthreads();
        const int base = (k1t << 9) + (k2t << 5);
        if (f == 0) {
            #pragma unroll
            for (int j2 = 0; j2 < 16; j2++) {
                float2 a = Z[base + (j2 ^ k2t)];
                float2 b = Z[base + (j2 ^ k2t) + 16];
                yy[j2] = cadd(a, b);
            }
        } else {
            #pragma unroll
            for (int j2 = 0; j2 < 16; j2++) {
                float2 a = Z[base + (j2 ^ k2t)];
                float2 b = Z[base + (j2 ^ k2t) + 16];
                yy[j2] = cmul(csub(a, b), make_float2(TW32R[j2], TW32I[j2]));
            }
        }
        __syncthreads();                         // all L2 reads done before spectrum store
        fft16(yy);
        #pragma unroll
        for (int p = 0; p < 16; p++) {
            int s2 = BR4[p];
            int k = k1t + (k2t << 4) + (f << 8) + (s2 << 9);
            Z[(k & ~31) | ((k & 31) ^ ((k >> 5) & 31))] = yy[p];  // natural k, swizzled low5
        }
        __syncthreads();                         // spectrum ready
    };

    float2 y[16];

    // -------- phase A: strain FFT + unpack S spectrum (16 bins/thread) --------
    float sre[16], sim[16];                      // S spectrum; later |H|^2 / Re(conj H * S)
    float s_nyq;
    do_fft(strn + (size_t)row * 16384, y);
    {
        const float2 cv = twB[t];
        #pragma unroll
        for (int i = 0; i < 16; i++) {
            int k = (t << 4) + i;
            int m = (8192 - k) & 8191;
            int ak = (k & ~31) | ((k & 31) ^ ((k >> 5) & 31));
            int am = (m & ~31) | ((m & 31) ^ ((m >> 5) & 31));
            float2 A = Z[ak], B = Z[am];
            float2 w = cmul(cv, twI[i]);         // W_16384^k
            float Er = 0.5f*(A.x + B.x), Ei = 0.5f*(A.y - B.y);
            float Dr = 0.5f*(A.x - B.x), Di = 0.5f*(A.y + B.y);
            sre[i] = Er + w.x*Di + w.y*Dr;
            sim[i] = Ei + w.y*Di - w.x*Dr;
        }
        float2 z0 = Z[0];
        s_nyq = z0.x - z0.y;
    }
    __syncthreads();                             // unpack reads done; Z free

    // -------- phase B: template FFT + unpack + in-place combine --------
    float h_nyq;
    do_fft(tmpl + (size_t)row * 16384, y);       // y reused: dead after phase A
    {
        const float2 cv = twB[t];
        #pragma unroll
        for (int i = 0; i < 16; i++) {
            int k = (t << 4) + i;
            int m = (8192 - k) & 8191;
            int ak = (k & ~31) | ((k & 31) ^ ((k >> 5) & 31));
            int am = (m & ~31) | ((m & 31) ^ ((m >> 5) & 31));
            float2 A = Z[ak], B = Z[am];
            float2 w = cmul(cv, twI[i]);
            float Er = 0.5f*(A.x + B.x), Ei = 0.5f*(A.y - B.y);
            float Dr = 0.5f*(A.x - B.x), Di = 0.5f*(A.y + B.y);
            float hr = Er + w.x*Di + w.y*Dr;
            float hi = Ei + w.y*Di - w.x*Dr;
            float pr = hr*sre[i] + hi*sim[i];    // Re(conj(H)*S)
            sre[i] = hr*hr + hi*hi;              // |H|^2 (in place)
            sim[i] = pr;
        }
        float2 z0 = Z[0];
        h_nyq = z0.x - z0.y;
    }
    __syncthreads();                             // unpack reads done; Z free for cum

    // -------- cum_h: wave shuffle scan over 8 waves --------
    const int SCANW = 8456;                      // beyond cum (<= F[8448])
    const int EDG   = 8466;                      // 17 ints
    const int BINS  = 8484;                      // 16 floats
    const int TOT   = 8501;

    float run = 0.f;
    #pragma unroll
    for (int i = 0; i < 16; i++) run += ALPHA * sre[i];

    const int lane = t & 63, wid = t >> 6;
    float v = run;
    #pragma unroll
    for (int off = 1; off < 64; off <<= 1) {
        float o = __shfl_up(v, off, 64);
        if (lane >= off) v += o;
    }
    if (lane == 63) F[SCANW + wid] = v;
    __syncthreads();
    float wbase = 0.f;
    #pragma unroll
    for (int w2 = 0; w2 < 7; w2++) if (w2 < wid) wbase += F[SCANW + w2];
    float base2 = wbase + v - run;               // exclusive prefix

    float cum = base2;
    #pragma unroll
    for (int i = 0; i < 16; i++) {               // cum at phys(k)=k+(k>>5)
        cum += ALPHA * sre[i];
        int k = (t << 4) + i;
        F[k + (k >> 5)] = cum;
    }
    if (t == 511) F[8448] = cum + ALPHA * h_nyq * h_nyq;   // cum_h[8192]
    __syncthreads();

    // -------- edges (searchsorted right) + bin init --------
    float total_h = F[8448];
    if (t < 17) {
        float target = (float)t * 0.0625f * total_h;
        int lo = 0, hi = 8193;
        while (lo < hi) {
            int mid = (lo + hi) >> 1;
            float vv = F[mid + (mid >> 5)];
            if (vv <= target) lo = mid + 1; else hi = mid;
        }
        I[EDG + t] = lo < 8192 ? lo : 8192;
    }
    if (t >= 64 && t < 80) F[BINS + (t - 64)] = 0.f;
    if (t == 80) F[TOT] = 0.f;
    __syncthreads();

    int e[17];
    #pragma unroll
    for (int i = 0; i < 17; i++) e[i] = I[EDG + i];

    float invs = 1.0f / sqrtf(total_h);
    float qs   = ALPHA * invs;

    // -------- segmented bin sums + total --------
    float tot = 0.f, acc = 0.f;
    int   cur = -1;
    #pragma unroll
    for (int i = 0; i < 16; i++) {
        int   k = (t << 4) + i;
        float r = qs * sim[i];
        tot += r;
        int bn = -1;                             // k in bin bn iff e[bn] < k <= e[bn+1]
        #pragma unroll
        for (int j = 0; j < 17; j++) bn += (e[j] < k) ? 1 : 0;
        if (bn != cur) {
            if (cur >= 0) atomicAdd(&F[BINS + cur], acc);
            acc = 0.f;
            cur = bn;
        }
        acc += r;
    }
    if (cur >= 0) atomicAdd(&F[BINS + cur], acc);

    #pragma unroll
    for (int off = 32; off > 0; off >>= 1) tot += __shfl_down(tot, off);
    if ((t & 63) == 0) atomicAdd(&F[TOT], tot);

    if (t == 0) {                                // Nyquist term (k = 8192)
        float rn = qs * (h_nyq * s_nyq);
        atomicAdd(&F[TOT], rn);
        int bn = -1;
        #pragma unroll
        for (int j = 0; j < 17; j++) bn += (e[j] < 8192) ? 1 : 0;
        if (bn >= 0) atomicAdd(&F[BINS + bn], rn);
    }
    __syncthreads();

    if (t == 0) {
        float total = F[TOT];
        float mean  = total * 0.0625f;
        float chisq = 0.f;
        #pragma unroll
        for (int j = 0; j < 16; j++) {
            float d = F[BINS + j] - mean;
            chisq += d * d;
        }
        out[row] = chisq * (16.0f / 15.0f);
    }
}

extern "C" void kernel_launch(void* const* d_in, const int* in_sizes, int n_in,
                              void* d_out, int out_size, void* d_ws, size_t ws_size,
                              hipStream_t stream) {
    const float* tmpl = (const float*)d_in[0];
    const float* strn = (const float*)d_in[1];
    float* outp = (float*)d_out;
    float2* ws  = (float2*)d_ws;                 // ~8.4 KiB twiddle tables

    int rows = in_sizes[0] / 16384;              // 1024

    hipLaunchKernelGGL(init_tw, dim3(2), dim3(1024), 0, stream, ws);
    hipLaunchKernelGGL(chisq_kernel, dim3(rows), dim3(512), 0, stream,
                       tmpl, strn, ws, outp);
}